// Round 7
// baseline (143.163 us; speedup 1.0000x reference)
//
#include <hip/hip_runtime.h>
#include <hip/hip_bf16.h>
#include <cstddef>

#define E_TOTAL 30000
#define INV_S3 0.57735026918962576f
#define PW0    0.10206207261596575f
#define PW1    0.17677669529663687f

typedef __attribute__((ext_vector_type(8))) short bf16x8;
typedef __attribute__((ext_vector_type(4))) float f32x4;

#define NA_SH (34*6*512)   /* B-alpha: K=1088 (34 chunks), N=96 */
#define NB_SH (17*4*512)   /* B-beta : K=544,  N=64 */
#define NC_SH (17*2*512)   /* B-gamma: K=544,  N=32 */
#define NH_BLKS 118

__device__ __forceinline__ short f2bf(float v) {
    union { __hip_bfloat16 h; short s; } u;
    u.h = __float2bfloat16(v);
    return u.s;
}
__device__ __forceinline__ f32x4 ld4(const float* p) {
    return *reinterpret_cast<const f32x4*>(p);
}

// ================= prep: h MLP + fragment-ordered B (verbatim from round 4) =
__global__ void prep_all(const float* __restrict__ dist, const float* __restrict__ freq,
                         const float* __restrict__ w1, const float* __restrict__ b1,
                         const float* __restrict__ w2, const float* __restrict__ b2,
                         float* __restrict__ h_out,
                         short* __restrict__ Ba, short* __restrict__ Bb, short* __restrict__ Bc)
{
    const float C1 = PW1 * INV_S3, C2 = PW0 * INV_S3;
    const int t = threadIdx.x;
    if (blockIdx.x < NH_BLKS) {
        int e = blockIdx.x * 256 + t;
        if (e >= E_TOTAL) return;
        float d  = dist[e] * 0.25f;
        float d2 = d * d, d5 = d2 * d2 * d;
        float env = 1.0f / d - 28.0f * d5 + 48.0f * d5 * d - 21.0f * d5 * d * d;
        env = (d < 1.0f) ? env : 0.0f;
        float basis[10];
#pragma unroll
        for (int k = 0; k < 10; ++k) basis[k] = env * sinf(freq[k] * d);
#pragma unroll
        for (int j = 0; j < 16; ++j) {
            float a = b1[j];
#pragma unroll
            for (int k = 0; k < 10; ++k) a = fmaf(basis[k], w1[k * 16 + j], a);
            h_out[(size_t)e * 16 + j] = a / (1.0f + __expf(-a));
        }
        return;
    }
    __shared__ float sw[3072];
    int blk = blockIdx.x - NH_BLKS;
    if (blk < 34) {                       // ---- Ba chunk ----
        int c = blk;
        int cc = (c < 17) ? c : c - 17;
        int ubase = (c < 17) ? 0 : 32;
        const float* src = (cc < 16) ? (w2 + (size_t)cc * 9216) : b2;
        const float4* pA = reinterpret_cast<const float4*>(src + ubase * 64);
        for (int i = t; i < 512; i += 256) reinterpret_cast<float4*>(sw)[i] = pA[i];
        const float4* pB = reinterpret_cast<const float4*>(src + 4096 + ubase * 32);
        if (t < 256) reinterpret_cast<float4*>(sw + 2048)[t] = pB[t];
        __syncthreads();
        for (int i = t; i < 384; i += 256) {
            int nt = i >> 6, lane = i & 63, kg = lane >> 4, jc = lane & 15;
            int w = nt * 16 + jc;
            bf16x8 fr;
#pragma unroll
            for (int b = 0; b < 8; ++b) {
                int u = kg * 8 + b;
                float v = (w < 64) ? PW0 * sw[u * 64 + w]
                                   : C1  * sw[2048 + u * 32 + (w - 64)];
                fr[b] = f2bf(v);
            }
            *reinterpret_cast<bf16x8*>(Ba + ((size_t)(c * 6 + nt)) * 512 + lane * 8) = fr;
        }
    } else if (blk < 51) {                // ---- Bb chunk (Wd region) ----
        int c = blk - 34;
        const float* src = (c < 16) ? (w2 + (size_t)c * 9216) : b2;
        const float4* p = reinterpret_cast<const float4*>(src + 7168);
        for (int i = t; i < 512; i += 256) reinterpret_cast<float4*>(sw)[i] = p[i];
        __syncthreads();
        {
            int nt = t >> 6, lane = t & 63, kg = lane >> 4, jc = lane & 15;
            int w = nt * 16 + jc;
            bf16x8 fr;
#pragma unroll
            for (int b = 0; b < 8; ++b) { int u = kg * 8 + b; fr[b] = f2bf(C2 * sw[u * 64 + w]); }
            *reinterpret_cast<bf16x8*>(Bb + ((size_t)(c * 4 + nt)) * 512 + lane * 8) = fr;
        }
    } else {                              // ---- Bc chunk (Wc region) ----
        int c = blk - 51;
        const float* src = (c < 16) ? (w2 + (size_t)c * 9216) : b2;
        const float4* p = reinterpret_cast<const float4*>(src + 6144);
        if (t < 256) reinterpret_cast<float4*>(sw)[t] = p[t];
        __syncthreads();
        if (t < 128) {
            int nt = t >> 6, lane = t & 63, kg = lane >> 4, jc = lane & 15;
            int w = nt * 16 + jc;
            bf16x8 fr;
#pragma unroll
            for (int b = 0; b < 8; ++b) { int u = kg * 8 + b; fr[b] = f2bf(C1 * sw[u * 32 + w]); }
            *reinterpret_cast<bf16x8*>(Bc + ((size_t)(c * 2 + nt)) * 512 + lane * 8) = fr;
        }
    }
}

// ================= step helpers (verbatim from round 4) =====================
__device__ __forceinline__ void mstep6(const bf16x8* __restrict__ Bp, int base, float hc,
                                       const float (&xs)[8], int lane, f32x4 (&acc)[6]) {
    bf16x8 af;
#pragma unroll
    for (int b = 0; b < 8; ++b) af[b] = f2bf(hc * xs[b]);
#pragma unroll
    for (int nt = 0; nt < 6; ++nt) {
        bf16x8 bc = Bp[(size_t)(base + nt) * 64 + lane];
        acc[nt] = __builtin_amdgcn_mfma_f32_16x16x32_bf16(af, bc, acc[nt], 0, 0, 0);
    }
}
__device__ __forceinline__ void mstep4(const bf16x8* __restrict__ Bp, int base, float hc,
                                       const float (&xs)[8], int lane, f32x4 (&acc)[4]) {
    bf16x8 af;
#pragma unroll
    for (int b = 0; b < 8; ++b) af[b] = f2bf(hc * xs[b]);
#pragma unroll
    for (int nt = 0; nt < 4; ++nt) {
        bf16x8 bc = Bp[(size_t)(base + nt) * 64 + lane];
        acc[nt] = __builtin_amdgcn_mfma_f32_16x16x32_bf16(af, bc, acc[nt], 0, 0, 0);
    }
}
__device__ __forceinline__ void gstep(const bf16x8* __restrict__ Bp, int base, float coef,
                                      const float (&x1w)[24], int lane, f32x4 (&acc)[3][2]) {
    bf16x8 am[3];
#pragma unroll
    for (int m = 0; m < 3; ++m)
#pragma unroll
        for (int b = 0; b < 8; ++b) am[m][b] = f2bf(coef * x1w[3 * b + m]);
#pragma unroll
    for (int nt = 0; nt < 2; ++nt) {
        bf16x8 bc = Bp[(size_t)(base + nt) * 64 + lane];
#pragma unroll
        for (int m = 0; m < 3; ++m)
            acc[m][nt] = __builtin_amdgcn_mfma_f32_16x16x32_bf16(am[m], bc, acc[m][nt], 0, 0, 0);
    }
}

// ================= main kernel: round-4 dataflow, interleaved chains ========
// Identical arithmetic to round 4 (per-accumulator chunk order preserved
// bit-for-bit). Only change: alpha-lo/beta/gamma steps interleaved in one
// loop so the scheduler sees 3 independent load->MFMA chains (ILP), instead
// of one serialized chain per phase.
__launch_bounds__(256, 2)
__global__ void conv_main(const float* __restrict__ x, const float* __restrict__ rp,
                          const float* __restrict__ h_arr,
                          const short* __restrict__ Ba, const short* __restrict__ Bb,
                          const short* __restrict__ Bc, float* __restrict__ out)
{
    __shared__ float ssh[64][4];
    const int t = threadIdx.x, lane = t & 63, wave = t >> 6;
    const int kg = lane >> 4, jc = lane & 15;
    const int e0 = blockIdx.x * 64;

    { int ee = t >> 2, c4 = t & 3;
      ssh[ee][c4] = (e0 + ee < E_TOTAL) ? rp[(size_t)(e0 + ee) * 4 + c4] : 0.f; }

    const int erow = wave * 16 + jc;
    const size_t eA = (size_t)(e0 + erow);
    const bool ev = (e0 + erow) < E_TOTAL;
    const float* xp = x + eA * 160;
    const float* hp = h_arr + eA * 16;

    float h[16];
#pragma unroll
    for (int i = 0; i < 4; ++i) {
        f32x4 q = ev ? ld4(hp + 4 * i) : f32x4{0.f, 0.f, 0.f, 0.f};
        h[4*i] = q[0]; h[4*i+1] = q[1]; h[4*i+2] = q[2]; h[4*i+3] = q[3];
    }
    float x0lo[8], x0hi[8];
#pragma unroll
    for (int i = 0; i < 2; ++i) {
        f32x4 q = ev ? ld4(xp + kg * 8 + 4 * i) : f32x4{0.f, 0.f, 0.f, 0.f};
        x0lo[4*i] = q[0]; x0lo[4*i+1] = q[1]; x0lo[4*i+2] = q[2]; x0lo[4*i+3] = q[3];
        f32x4 r = ev ? ld4(xp + 32 + kg * 8 + 4 * i) : f32x4{0.f, 0.f, 0.f, 0.f};
        x0hi[4*i] = r[0]; x0hi[4*i+1] = r[1]; x0hi[4*i+2] = r[2]; x0hi[4*i+3] = r[3];
    }
    float x1w[24];
#pragma unroll
    for (int i = 0; i < 6; ++i) {
        f32x4 q = ev ? ld4(xp + 64 + 24 * kg + 4 * i) : f32x4{0.f, 0.f, 0.f, 0.f};
        x1w[4*i] = q[0]; x1w[4*i+1] = q[1]; x1w[4*i+2] = q[2]; x1w[4*i+3] = q[3];
    }
    __syncthreads();

    const float sh0 = ssh[erow][0];
    float z[8];
    { float s1 = ssh[erow][1], s2 = ssh[erow][2], s3 = ssh[erow][3];
#pragma unroll
      for (int u = 0; u < 8; ++u)
          z[u] = x1w[3*u] * s1 + x1w[3*u+1] * s2 + x1w[3*u+2] * s3; }

    const bf16x8* BpA = reinterpret_cast<const bf16x8*>(Ba);
    const bf16x8* BpB = reinterpret_cast<const bf16x8*>(Bb);
    const bf16x8* BpC = reinterpret_cast<const bf16x8*>(Bc);

    f32x4 accA[6] = {};
    f32x4 accB[4] = {};
    f32x4 accG[3][2] = {};

    // ---- interleaved: alpha-lo + beta + gamma (3 independent chains) ----
#pragma unroll
    for (int c = 0; c < 16; ++c) {
        mstep6(BpA, c * 6, h[c], x0lo, lane, accA);
        mstep4(BpB, c * 4, h[c], z, lane, accB);
        gstep (BpC, c * 2, sh0 * h[c], x1w, lane, accG);
    }
    mstep6(BpA, 16 * 6, 1.0f, x0lo, lane, accA);
    mstep4(BpB, 16 * 4, 1.0f, z, lane, accB);
    gstep (BpC, 16 * 2, sh0, x1w, lane, accG);

    // ---- alpha-hi ----
#pragma unroll
    for (int c = 0; c < 16; ++c) mstep6(BpA, (17 + c) * 6, h[c], x0hi, lane, accA);
    mstep6(BpA, 33 * 6, 1.0f, x0hi, lane, accA);

    // ---- out0 epilogue: sh0*alpha + beta ----
#pragma unroll
    for (int nt = 0; nt < 4; ++nt)
#pragma unroll
        for (int r = 0; r < 4; ++r) {
            int row = wave * 16 + 4 * kg + r;
            if (e0 + row < E_TOTAL)
                out[(size_t)(e0 + row) * 160 + nt * 16 + jc] =
                    ssh[row][0] * accA[nt][r] + accB[nt][r];
        }

    // ---- out1 epilogue: tb*sh1[m] + tc (tb = accA[4+nt]) ----
#pragma unroll
    for (int m = 0; m < 3; ++m)
#pragma unroll
        for (int nt = 0; nt < 2; ++nt)
#pragma unroll
            for (int r = 0; r < 4; ++r) {
                int row = wave * 16 + 4 * kg + r;
                int w = nt * 16 + jc;
                if (e0 + row < E_TOTAL)
                    out[(size_t)(e0 + row) * 160 + 64 + w * 3 + m] =
                        accA[4 + nt][r] * ssh[row][1 + m] + accG[m][nt][r];
            }
}

extern "C" void kernel_launch(void* const* d_in, const int* in_sizes, int n_in,
                              void* d_out, int out_size, void* d_ws, size_t ws_size,
                              hipStream_t stream) {
    const float* x    = (const float*)d_in[0];
    const float* rp   = (const float*)d_in[1];
    const float* dist = (const float*)d_in[2];
    const float* freq = (const float*)d_in[3];
    const float* w1   = (const float*)d_in[4];
    const float* b1   = (const float*)d_in[5];
    const float* w2   = (const float*)d_in[6];
    const float* b2   = (const float*)d_in[7];
    float* out = (float*)d_out;

    float* h_arr = (float*)d_ws;                           // 30000*16*4 = 1.92 MB
    short* Ba = (short*)((char*)d_ws + 1920000);
    short* Bb = Ba + NA_SH;
    short* Bc = Bb + NB_SH;

    prep_all<<<NH_BLKS + 68, 256, 0, stream>>>(dist, freq, w1, b1, w2, b2,
                                               h_arr, Ba, Bb, Bc);
    conv_main<<<(E_TOTAL + 63) / 64, 256, 0, stream>>>(x, rp, h_arr, Ba, Bb, Bc, out);
}

// Round 8
// 105.371 us; speedup vs baseline: 1.3587x; 1.3587x over previous
//
#include <hip/hip_runtime.h>
#include <hip/hip_bf16.h>
#include <cstddef>

#define E_TOTAL 30000
#define INV_S3 0.57735026918962576f
#define PW0    0.10206207261596575f
#define PW1    0.17677669529663687f

typedef __attribute__((ext_vector_type(8))) short bf16x8;
typedef __attribute__((ext_vector_type(4))) float f32x4;

#define NA_SH (34*6*512)   /* B-alpha: K=1088 (34 chunks), N=96 */
#define NB_SH (17*4*512)   /* B-beta : K=544,  N=64 */
#define NC_SH (17*2*512)   /* B-gamma: K=544,  N=32 */
#define NH_BLKS 118

__device__ __forceinline__ short f2bf(float v) {
    union { __hip_bfloat16 h; short s; } u;
    u.h = __float2bfloat16(v);
    return u.s;
}
__device__ __forceinline__ f32x4 ld4(const float* p) {
    return *reinterpret_cast<const f32x4*>(p);
}

// async global->LDS, 16B per lane; dest must be wave-uniform-base + lane*16
#define GL16(gp, lp) __builtin_amdgcn_global_load_lds( \
    (const __attribute__((address_space(1))) void*)(gp), \
    (__attribute__((address_space(3))) void*)(lp), 16, 0, 0)

// ================= prep: h MLP + fragment-ordered B (verbatim from round 4) =
__global__ void prep_all(const float* __restrict__ dist, const float* __restrict__ freq,
                         const float* __restrict__ w1, const float* __restrict__ b1,
                         const float* __restrict__ w2, const float* __restrict__ b2,
                         float* __restrict__ h_out,
                         short* __restrict__ Ba, short* __restrict__ Bb, short* __restrict__ Bc)
{
    const float C1 = PW1 * INV_S3, C2 = PW0 * INV_S3;
    const int t = threadIdx.x;
    if (blockIdx.x < NH_BLKS) {
        int e = blockIdx.x * 256 + t;
        if (e >= E_TOTAL) return;
        float d  = dist[e] * 0.25f;
        float d2 = d * d, d5 = d2 * d2 * d;
        float env = 1.0f / d - 28.0f * d5 + 48.0f * d5 * d - 21.0f * d5 * d * d;
        env = (d < 1.0f) ? env : 0.0f;
        float basis[10];
#pragma unroll
        for (int k = 0; k < 10; ++k) basis[k] = env * sinf(freq[k] * d);
#pragma unroll
        for (int j = 0; j < 16; ++j) {
            float a = b1[j];
#pragma unroll
            for (int k = 0; k < 10; ++k) a = fmaf(basis[k], w1[k * 16 + j], a);
            h_out[(size_t)e * 16 + j] = a / (1.0f + __expf(-a));
        }
        return;
    }
    __shared__ float sw[3072];
    int blk = blockIdx.x - NH_BLKS;
    if (blk < 34) {                       // ---- Ba chunk ----
        int c = blk;
        int cc = (c < 17) ? c : c - 17;
        int ubase = (c < 17) ? 0 : 32;
        const float* src = (cc < 16) ? (w2 + (size_t)cc * 9216) : b2;
        const float4* pA = reinterpret_cast<const float4*>(src + ubase * 64);
        for (int i = t; i < 512; i += 256) reinterpret_cast<float4*>(sw)[i] = pA[i];
        const float4* pB = reinterpret_cast<const float4*>(src + 4096 + ubase * 32);
        if (t < 256) reinterpret_cast<float4*>(sw + 2048)[t] = pB[t];
        __syncthreads();
        for (int i = t; i < 384; i += 256) {
            int nt = i >> 6, lane = i & 63, kg = lane >> 4, jc = lane & 15;
            int w = nt * 16 + jc;
            bf16x8 fr;
#pragma unroll
            for (int b = 0; b < 8; ++b) {
                int u = kg * 8 + b;
                float v = (w < 64) ? PW0 * sw[u * 64 + w]
                                   : C1  * sw[2048 + u * 32 + (w - 64)];
                fr[b] = f2bf(v);
            }
            *reinterpret_cast<bf16x8*>(Ba + ((size_t)(c * 6 + nt)) * 512 + lane * 8) = fr;
        }
    } else if (blk < 51) {                // ---- Bb chunk (Wd region) ----
        int c = blk - 34;
        const float* src = (c < 16) ? (w2 + (size_t)c * 9216) : b2;
        const float4* p = reinterpret_cast<const float4*>(src + 7168);
        for (int i = t; i < 512; i += 256) reinterpret_cast<float4*>(sw)[i] = p[i];
        __syncthreads();
        {
            int nt = t >> 6, lane = t & 63, kg = lane >> 4, jc = lane & 15;
            int w = nt * 16 + jc;
            bf16x8 fr;
#pragma unroll
            for (int b = 0; b < 8; ++b) { int u = kg * 8 + b; fr[b] = f2bf(C2 * sw[u * 64 + w]); }
            *reinterpret_cast<bf16x8*>(Bb + ((size_t)(c * 4 + nt)) * 512 + lane * 8) = fr;
        }
    } else {                              // ---- Bc chunk (Wc region) ----
        int c = blk - 51;
        const float* src = (c < 16) ? (w2 + (size_t)c * 9216) : b2;
        const float4* p = reinterpret_cast<const float4*>(src + 6144);
        if (t < 256) reinterpret_cast<float4*>(sw)[t] = p[t];
        __syncthreads();
        if (t < 128) {
            int nt = t >> 6, lane = t & 63, kg = lane >> 4, jc = lane & 15;
            int w = nt * 16 + jc;
            bf16x8 fr;
#pragma unroll
            for (int b = 0; b < 8; ++b) { int u = kg * 8 + b; fr[b] = f2bf(C1 * sw[u * 32 + w]); }
            *reinterpret_cast<bf16x8*>(Bc + ((size_t)(c * 2 + nt)) * 512 + lane * 8) = fr;
        }
    }
}

// stage step c: [alpha-lo(c) 3072sh | alpha-hi(c) 3072sh | beta(c) 2048sh]
// All calls wave-uniform-active; lanes linear -> valid global_load_lds dest.
__device__ __forceinline__ void stage_chunk(const short* __restrict__ Ba,
                                            const short* __restrict__ Bb,
                                            short* dst, int c, int t) {
    const short* slo = Ba + c * 3072;
    const short* shi = Ba + (17 + c) * 3072;
    const short* sbt = Bb + c * 2048;
    GL16(slo + t * 8,            dst + t * 8);
    if (t < 128) GL16(slo + (t + 256) * 8, dst + (t + 256) * 8);
    GL16(shi + t * 8,            dst + 3072 + t * 8);
    if (t < 128) GL16(shi + (t + 256) * 8, dst + 3072 + (t + 256) * 8);
    GL16(sbt + t * 8,            dst + 6144 + t * 8);
}

// ================= main kernel: r4 dataflow + LDS-staged B ==================
// wave = m-tile (16 edges); lane (kg,jc): A-edge = wave*16+jc, k-window kg*8+b.
// B double-buffered in LDS via global_load_lds (16KB/step, 1 barrier/step);
// gamma's whole B (34KB) LDS-resident from the prologue.
__launch_bounds__(256, 2)
__global__ void conv_main(const float* __restrict__ x, const float* __restrict__ rp,
                          const float* __restrict__ h_arr,
                          const short* __restrict__ Ba, const short* __restrict__ Bb,
                          const short* __restrict__ Bc, float* __restrict__ out)
{
    __shared__ __align__(16) char smem[68608];
    short* sgam = reinterpret_cast<short*>(smem);            // 34816 B
    short* sstg = reinterpret_cast<short*>(smem + 34816);    // 2 x 16384 B
    float (*ssh)[4] = reinterpret_cast<float(*)[4]>(smem + 67584);

    const int t = threadIdx.x, lane = t & 63, wave = t >> 6;
    const int kg = lane >> 4, jc = lane & 15;
    const int e0 = blockIdx.x * 64;

    // ---- prologue: issue long-latency loads first ----
#pragma unroll
    for (int k2 = 0; k2 < 8; ++k2)
        GL16(Bc + (t + k2 * 256) * 8, sgam + (t + k2 * 256) * 8);
    if (t < 128) GL16(Bc + (t + 2048) * 8, sgam + (t + 2048) * 8);
    stage_chunk(Ba, Bb, sstg, 0, t);

    { int ee = t >> 2, c4 = t & 3;
      ssh[ee][c4] = (e0 + ee < E_TOTAL) ? rp[(size_t)(e0 + ee) * 4 + c4] : 0.f; }

    const int erow = wave * 16 + jc;
    const size_t eAi = (size_t)(e0 + erow);
    const bool ev = (e0 + erow) < E_TOTAL;
    const float* xp = x + eAi * 160;
    const float* hp = h_arr + eAi * 16;

    float h[16];
#pragma unroll
    for (int i = 0; i < 4; ++i) {
        f32x4 q = ev ? ld4(hp + 4 * i) : f32x4{0.f, 0.f, 0.f, 0.f};
        h[4*i] = q[0]; h[4*i+1] = q[1]; h[4*i+2] = q[2]; h[4*i+3] = q[3];
    }
    float x0lo[8], x0hi[8];
#pragma unroll
    for (int i = 0; i < 2; ++i) {
        f32x4 q = ev ? ld4(xp + kg * 8 + 4 * i) : f32x4{0.f, 0.f, 0.f, 0.f};
        x0lo[4*i] = q[0]; x0lo[4*i+1] = q[1]; x0lo[4*i+2] = q[2]; x0lo[4*i+3] = q[3];
        f32x4 r = ev ? ld4(xp + 32 + kg * 8 + 4 * i) : f32x4{0.f, 0.f, 0.f, 0.f};
        x0hi[4*i] = r[0]; x0hi[4*i+1] = r[1]; x0hi[4*i+2] = r[2]; x0hi[4*i+3] = r[3];
    }
    float x1w[24];
#pragma unroll
    for (int i = 0; i < 6; ++i) {
        f32x4 q = ev ? ld4(xp + 64 + 24 * kg + 4 * i) : f32x4{0.f, 0.f, 0.f, 0.f};
        x1w[4*i] = q[0]; x1w[4*i+1] = q[1]; x1w[4*i+2] = q[2]; x1w[4*i+3] = q[3];
    }
    __syncthreads();   // drains gamma-load + stage0 + ssh writes

    const float sh0 = ssh[erow][0];
    float z[8];
    { float s1 = ssh[erow][1], s2 = ssh[erow][2], s3 = ssh[erow][3];
#pragma unroll
      for (int u = 0; u < 8; ++u)
          z[u] = x1w[3*u] * s1 + x1w[3*u+1] * s2 + x1w[3*u+2] * s3; }

    f32x4 accA[6] = {};
    f32x4 accB[4] = {};
    f32x4 accG[3][2] = {};

    // ======== main loop: 17 steps, double-buffered LDS B ====================
    int cur = 0;
#pragma unroll
    for (int c = 0; c < 17; ++c) {
        short* buf = sstg + cur * 8192;
        if (c < 16) stage_chunk(Ba, Bb, sstg + (cur ^ 1) * 8192, c + 1, t);

        const float hc = (c < 16) ? h[c] : 1.0f;
        bf16x8 blo[6], bhi[6], bbt[4];
#pragma unroll
        for (int nt = 0; nt < 6; ++nt) {
            blo[nt] = *reinterpret_cast<const bf16x8*>(buf + nt * 512 + lane * 8);
            bhi[nt] = *reinterpret_cast<const bf16x8*>(buf + 3072 + nt * 512 + lane * 8);
        }
#pragma unroll
        for (int nt = 0; nt < 4; ++nt)
            bbt[nt] = *reinterpret_cast<const bf16x8*>(buf + 6144 + nt * 512 + lane * 8);

        bf16x8 aflo, afhi, afz;
#pragma unroll
        for (int b = 0; b < 8; ++b) {
            aflo[b] = f2bf(hc * x0lo[b]);
            afhi[b] = f2bf(hc * x0hi[b]);
            afz[b]  = f2bf(hc * z[b]);
        }
#pragma unroll
        for (int nt = 0; nt < 6; ++nt) {
            accA[nt] = __builtin_amdgcn_mfma_f32_16x16x32_bf16(aflo, blo[nt], accA[nt], 0, 0, 0);
            accA[nt] = __builtin_amdgcn_mfma_f32_16x16x32_bf16(afhi, bhi[nt], accA[nt], 0, 0, 0);
        }
#pragma unroll
        for (int nt = 0; nt < 4; ++nt)
            accB[nt] = __builtin_amdgcn_mfma_f32_16x16x32_bf16(afz, bbt[nt], accB[nt], 0, 0, 0);

        __syncthreads();   // next stage complete; cur buf free to overwrite
        cur ^= 1;
    }

    // ---- out0 epilogue: sh0*alpha + beta ----
#pragma unroll
    for (int nt = 0; nt < 4; ++nt)
#pragma unroll
        for (int r = 0; r < 4; ++r) {
            int row = wave * 16 + 4 * kg + r;
            if (e0 + row < E_TOTAL)
                out[(size_t)(e0 + row) * 160 + nt * 16 + jc] =
                    ssh[row][0] * accA[nt][r] + accB[nt][r];
        }

    // ======== gamma: LDS-resident B, 17 steps ===============================
#pragma unroll
    for (int c = 0; c < 17; ++c) {
        const float coef = (c < 16) ? sh0 * h[c] : sh0;
        bf16x8 bg[2];
#pragma unroll
        for (int nt = 0; nt < 2; ++nt)
            bg[nt] = *reinterpret_cast<const bf16x8*>(sgam + (c * 2 + nt) * 512 + lane * 8);
        bf16x8 am[3];
#pragma unroll
        for (int m = 0; m < 3; ++m)
#pragma unroll
            for (int b = 0; b < 8; ++b) am[m][b] = f2bf(coef * x1w[3 * b + m]);
#pragma unroll
        for (int nt = 0; nt < 2; ++nt)
#pragma unroll
            for (int m = 0; m < 3; ++m)
                accG[m][nt] = __builtin_amdgcn_mfma_f32_16x16x32_bf16(am[m], bg[nt], accG[m][nt], 0, 0, 0);
    }

    // ---- out1 epilogue: tb*sh1[m] + tc (tb = accA[4+nt]) ----
#pragma unroll
    for (int m = 0; m < 3; ++m)
#pragma unroll
        for (int nt = 0; nt < 2; ++nt)
#pragma unroll
            for (int r = 0; r < 4; ++r) {
                int row = wave * 16 + 4 * kg + r;
                int w = nt * 16 + jc;
                if (e0 + row < E_TOTAL)
                    out[(size_t)(e0 + row) * 160 + 64 + w * 3 + m] =
                        accA[4 + nt][r] * ssh[row][1 + m] + accG[m][nt][r];
            }
}

extern "C" void kernel_launch(void* const* d_in, const int* in_sizes, int n_in,
                              void* d_out, int out_size, void* d_ws, size_t ws_size,
                              hipStream_t stream) {
    const float* x    = (const float*)d_in[0];
    const float* rp   = (const float*)d_in[1];
    const float* dist = (const float*)d_in[2];
    const float* freq = (const float*)d_in[3];
    const float* w1   = (const float*)d_in[4];
    const float* b1   = (const float*)d_in[5];
    const float* w2   = (const float*)d_in[6];
    const float* b2   = (const float*)d_in[7];
    float* out = (float*)d_out;

    float* h_arr = (float*)d_ws;                           // 30000*16*4 = 1.92 MB
    short* Ba = (short*)((char*)d_ws + 1920000);
    short* Bb = Ba + NA_SH;
    short* Bc = Bb + NB_SH;

    prep_all<<<NH_BLKS + 68, 256, 0, stream>>>(dist, freq, w1, b1, w2, b2,
                                               h_arr, Ba, Bb, Bc);
    conv_main<<<(E_TOTAL + 63) / 64, 256, 0, stream>>>(x, rp, h_arr, Ba, Bb, Bc, out);
}